// Round 1
// baseline (1024.691 us; speedup 1.0000x reference)
//
#include <hip/hip_runtime.h>

// Y[j, b, i] = ((2*x[i,j]+1) >> min(2047-b, 31)) & 1, as float32.
// Y shape [2048, 2048, 64]; nonzero only for b >= 2036 (v < 2^12).
// Pure write-bound: 1 GiB output, float4-vectorized stores.

#define EMB 2048
#define BATCH 64

__global__ __launch_bounds__(256) void emb_bits_kernel(
    const int* __restrict__ x, float4* __restrict__ out) {
    // quad index over the whole output: 2048*2048*64/4 = 2^26 quads
    unsigned int q  = blockIdx.x * 256u + threadIdx.x;
    unsigned int i4 = q & 15u;        // which float4 within the 64-wide batch dim
    unsigned int jb = q >> 4;         // j*2048 + b
    unsigned int b  = jb & 2047u;
    unsigned int j  = jb >> 11;
    int shift = 2047 - (int)b;

    float4 val = make_float4(0.f, 0.f, 0.f, 0.f);
    if (shift <= 11) {                // only last 12 columns carry data
        unsigned int i0 = i4 * 4u;
        int v0 = 2 * x[(i0 + 0) * EMB + j] + 1;
        int v1 = 2 * x[(i0 + 1) * EMB + j] + 1;
        int v2 = 2 * x[(i0 + 2) * EMB + j] + 1;
        int v3 = 2 * x[(i0 + 3) * EMB + j] + 1;
        val.x = (float)((v0 >> shift) & 1);
        val.y = (float)((v1 >> shift) & 1);
        val.z = (float)((v2 >> shift) & 1);
        val.w = (float)((v3 >> shift) & 1);
    }
    out[q] = val;
}

extern "C" void kernel_launch(void* const* d_in, const int* in_sizes, int n_in,
                              void* d_out, int out_size, void* d_ws, size_t ws_size,
                              hipStream_t stream) {
    const int* x = (const int*)d_in[0];
    float4* out = (float4*)d_out;
    const unsigned int quads = (unsigned int)EMB * EMB * BATCH / 4u; // 67108864
    dim3 grid(quads / 256u);                                        // 262144 blocks
    emb_bits_kernel<<<grid, dim3(256), 0, stream>>>(x, out);
}